// Round 14
// baseline (432.823 us; speedup 1.0000x reference)
//
#include <hip/hip_runtime.h>
#include <hip/hip_fp16.h>

#define SLOPE 0.2f

__device__ __forceinline__ float lrelu(float v) { return v >= 0.f ? v : SLOPE * v; }

__device__ __forceinline__ unsigned pack2(float a, float b) {
    __half2 h = __floats2half2_rn(a, b);
    return *reinterpret_cast<unsigned*>(&h);
}
__device__ __forceinline__ float4 h4tof4(uint2 u) {
    __half2 a = *reinterpret_cast<__half2*>(&u.x);
    __half2 b = *reinterpret_cast<__half2*>(&u.y);
    float2 fa = __half22float2(a), fb = __half22float2(b);
    return make_float4(fa.x, fa.y, fb.x, fb.y);
}
__device__ __forceinline__ void acc8(float4& A, float4& B, float a, uint4 u) {
    float4 lo = h4tof4(make_uint2(u.x, u.y));
    float4 hi = h4tof4(make_uint2(u.z, u.w));
    A.x += a * lo.x; A.y += a * lo.y; A.z += a * lo.z; A.w += a * lo.w;
    B.x += a * hi.x; B.y += a * hi.y; B.z += a * hi.z; B.w += a * hi.w;
}

// ============================================================================
// xp = x @ W (K -> 128 = 2 heads * 64) + attention dots, block-tile GEMM.
// ============================================================================
template <int K>
__global__ __launch_bounds__(256)
void k_xp_gemm(const float* __restrict__ x, const float* __restrict__ W,
               const float* __restrict__ as_, const float* __restrict__ ad_,
               __half* __restrict__ xph, float* __restrict__ asrc,
               float* __restrict__ adst, int N) {
    constexpr int ZS = K + 1;
    __shared__ float zs[64 * ZS];
    __shared__ float ws[K * 128];
    const int n0 = blockIdx.x * 64;
    const int t = threadIdx.x;

    for (int i = t; i < K * 32; i += 256) ((float4*)ws)[i] = ((const float4*)W)[i];
    for (int i = t; i < 64 * K; i += 256) {
        int n = i / K, k = i - n * K;
        int gn = n0 + n;
        zs[n * ZS + k] = (gn < N) ? x[(size_t)gn * K + k] : 0.f;
    }
    __syncthreads();

    const int tx = t & 15, ty = t >> 4;
    const int c0a = tx * 4;
    const int c0b = 64 + tx * 4;

    float4 asA = *(const float4*)(as_ + c0a);
    float4 asB = *(const float4*)(as_ + c0b);
    float4 adA = *(const float4*)(ad_ + c0a);
    float4 adB = *(const float4*)(ad_ + c0b);

    float acc[4][8];
    #pragma unroll
    for (int i = 0; i < 4; ++i)
        #pragma unroll
        for (int j = 0; j < 8; ++j) acc[i][j] = 0.f;

    for (int k = 0; k < K; ++k) {
        float4 w0 = *(const float4*)(ws + k * 128 + c0a);
        float4 w1 = *(const float4*)(ws + k * 128 + c0b);
        #pragma unroll
        for (int i = 0; i < 4; ++i) {
            float zv = zs[(ty * 4 + i) * ZS + k];
            acc[i][0] += zv * w0.x; acc[i][1] += zv * w0.y;
            acc[i][2] += zv * w0.z; acc[i][3] += zv * w0.w;
            acc[i][4] += zv * w1.x; acc[i][5] += zv * w1.y;
            acc[i][6] += zv * w1.z; acc[i][7] += zv * w1.w;
        }
    }

    #pragma unroll
    for (int i = 0; i < 4; ++i) {
        int nl = ty * 4 + i, gn = n0 + nl;
        if (gn < N) {
            uint2 ua, ub;
            ua.x = pack2(acc[i][0], acc[i][1]);
            ua.y = pack2(acc[i][2], acc[i][3]);
            ub.x = pack2(acc[i][4], acc[i][5]);
            ub.y = pack2(acc[i][6], acc[i][7]);
            *(uint2*)(xph + (size_t)gn * 128 + c0a) = ua;
            *(uint2*)(xph + (size_t)gn * 128 + c0b) = ub;
        }
        float ps0 = acc[i][0]*asA.x + acc[i][1]*asA.y + acc[i][2]*asA.z + acc[i][3]*asA.w;
        float ps1 = acc[i][4]*asB.x + acc[i][5]*asB.y + acc[i][6]*asB.z + acc[i][7]*asB.w;
        float pd0 = acc[i][0]*adA.x + acc[i][1]*adA.y + acc[i][2]*adA.z + acc[i][3]*adA.w;
        float pd1 = acc[i][4]*adB.x + acc[i][5]*adB.y + acc[i][6]*adB.z + acc[i][7]*adB.w;
        #pragma unroll
        for (int off = 1; off <= 8; off <<= 1) {
            ps0 += __shfl_xor(ps0, off, 64);
            ps1 += __shfl_xor(ps1, off, 64);
            pd0 += __shfl_xor(pd0, off, 64);
            pd1 += __shfl_xor(pd1, off, 64);
        }
        if (tx == 0 && gn < N) {
            asrc[gn * 2]     = ps0;
            asrc[gn * 2 + 1] = ps1;
            adst[gn * 2]     = pd0;
            adst[gn * 2 + 1] = pd1;
        }
    }
}

// ============================================================================
// CSR build: histogram(+rank capture) -> scan -> atomic-free scatter.
// ============================================================================
__global__ void k_hist(const int* __restrict__ dst, int* __restrict__ deg,
                       int* __restrict__ rank, int E) {
    int e = blockIdx.x * blockDim.x + threadIdx.x;
    if (e < E) rank[e] = atomicAdd(&deg[dst[e]], 1);
}

__global__ void k_scan_partial(const int* __restrict__ deg, int* __restrict__ partial, int N) {
    int b = blockIdx.x, t = threadIdx.x;
    int base = b * 1024 + t * 4;
    int s = 0;
    for (int i = 0; i < 4; ++i) { int idx = base + i; if (idx < N) s += deg[idx]; }
    __shared__ int sh[256];
    sh[t] = s; __syncthreads();
    for (int off = 128; off > 0; off >>= 1) { if (t < off) sh[t] += sh[t + off]; __syncthreads(); }
    if (t == 0) partial[b] = sh[0];
}

__global__ void k_scan_final(const int* __restrict__ deg, const int* __restrict__ partial,
                             int* __restrict__ rowptr, int N, int E, int nb) {
    int b = blockIdx.x, t = threadIdx.x;
    __shared__ int shp[256];
    shp[t] = (t < nb) ? partial[t] : 0;
    __syncthreads();
    for (int off = 1; off < 256; off <<= 1) {
        int v = (t >= off) ? shp[t - off] : 0;
        __syncthreads();
        shp[t] += v;
        __syncthreads();
    }
    int pbase = (b > 0) ? shp[b - 1] : 0;
    __syncthreads();

    int base = b * 1024 + t * 4;
    int local[4]; int s = 0;
    for (int i = 0; i < 4; ++i) { int idx = base + i; local[i] = (idx < N) ? deg[idx] : 0; s += local[i]; }
    __shared__ int sh[256];
    int orig = s;
    sh[t] = s; __syncthreads();
    for (int off = 1; off < 256; off <<= 1) {
        int v = (t >= off) ? sh[t - off] : 0;
        __syncthreads();
        sh[t] += v;
        __syncthreads();
    }
    int run = pbase + sh[t] - orig;
    for (int i = 0; i < 4; ++i) {
        int idx = base + i;
        if (idx < N) rowptr[idx] = run;
        run += local[i];
    }
    if (b == 0 && t == 0) rowptr[N] = E;
}

__global__ void k_scatter(const int* __restrict__ src, const int* __restrict__ dst,
                          const int* __restrict__ rowptr, const int* __restrict__ rank,
                          int* __restrict__ csr_src, int E) {
    int e = blockIdx.x * blockDim.x + threadIdx.x;
    if (e >= E) return;
    int d = dst[e];
    csr_src[rowptr[d] + rank[e]] = src[e];
}

// ============================================================================
// FUSED softmax + gather (layer 1): writes hout. One wave per node.
// ============================================================================
__global__ void k_ag(const int* __restrict__ rowptr, const int* __restrict__ csr_src,
                     const float* __restrict__ asrc, const float* __restrict__ adst,
                     const __half* __restrict__ xph, const float* __restrict__ b,
                     float* __restrict__ hout, int N) {
    int tid = blockIdx.x * blockDim.x + threadIdx.x;
    int lane = threadIdx.x & 63;
    int wid = tid >> 6;
    int nw = (gridDim.x * blockDim.x) >> 6;
    const int l  = lane & 31;
    const int hh = lane >> 5;
    const int g8 = (lane >> 3) & 3;
    const int c8 = lane & 7;
    const uint4* xp4 = (const uint4*)xph;
    float4 bb0 = ((const float4*)b)[c8 * 2];
    float4 bb1 = ((const float4*)b)[c8 * 2 + 1];

    for (int n = wid; n < N; n += nw) {
        int rs = rowptr[n], re = rowptr[n + 1], cnt = re - rs;
        float a_dst = adst[n * 2 + hh];
        float eself = __expf(lrelu(asrc[n * 2 + hh] + a_dst));

        float4 accA = make_float4(0.f, 0.f, 0.f, 0.f);
        float4 accB = make_float4(0.f, 0.f, 0.f, 0.f);

        if (cnt <= 32) {
            float ev = 0.f; int s_reg = n;
            if (l < cnt) {
                s_reg = csr_src[rs + l];
                ev = __expf(lrelu(asrc[s_reg * 2 + hh] + a_dst));
            }
            float den = ev + (l == 0 ? eself : 0.f);
            #pragma unroll
            for (int off = 16; off > 0; off >>= 1) den += __shfl_xor(den, off, 64);
            float inv = 1.f / (den + 1e-16f);
            float alpha_l = ev * inv;

            if (g8 == 0) acc8(accA, accB, eself * inv, xp4[(size_t)n * 16 + hh * 8 + c8]);
            int base = (hh << 5) - rs;
            for (int e0 = rs; e0 < re; e0 += 8) {
                int ea = e0 + g8, eb = e0 + 4 + g8;
                bool va = ea < re, vb = eb < re;
                float aa = __shfl(alpha_l, base + ea, 64);
                int   sa = __shfl(s_reg,   base + ea, 64);
                float ab = __shfl(alpha_l, base + eb, 64);
                int   sb = __shfl(s_reg,   base + eb, 64);
                if (!va) { aa = 0.f; sa = n; }
                if (!vb) { ab = 0.f; sb = n; }
                uint4 u1 = xp4[(size_t)sa * 16 + hh * 8 + c8];
                uint4 u2 = xp4[(size_t)sb * 16 + hh * 8 + c8];
                acc8(accA, accB, aa, u1);
                acc8(accA, accB, ab, u2);
            }
        } else {
            float den = (l == 0) ? eself : 0.f;
            for (int e = rs + l; e < re; e += 32)
                den += __expf(lrelu(asrc[csr_src[e] * 2 + hh] + a_dst));
            #pragma unroll
            for (int off = 16; off > 0; off >>= 1) den += __shfl_xor(den, off, 64);
            float inv = 1.f / (den + 1e-16f);
            if (g8 == 0) acc8(accA, accB, eself * inv, xp4[(size_t)n * 16 + hh * 8 + c8]);
            for (int e0 = rs; e0 < re; e0 += 8) {
                int ea = e0 + g8, eb = e0 + 4 + g8;
                bool va = ea < re, vb = eb < re;
                int sa = va ? csr_src[ea] : n;
                int sb = vb ? csr_src[eb] : n;
                float aa = va ? __expf(lrelu(asrc[sa * 2 + hh] + a_dst)) * inv : 0.f;
                float ab = vb ? __expf(lrelu(asrc[sb * 2 + hh] + a_dst)) * inv : 0.f;
                uint4 u1 = xp4[(size_t)sa * 16 + hh * 8 + c8];
                uint4 u2 = xp4[(size_t)sb * 16 + hh * 8 + c8];
                acc8(accA, accB, aa, u1);
                acc8(accA, accB, ab, u2);
            }
        }

        #pragma unroll
        for (int off = 8; off <= 32; off <<= 1) {
            accA.x += __shfl_xor(accA.x, off, 64);
            accA.y += __shfl_xor(accA.y, off, 64);
            accA.z += __shfl_xor(accA.z, off, 64);
            accA.w += __shfl_xor(accA.w, off, 64);
            accB.x += __shfl_xor(accB.x, off, 64);
            accB.y += __shfl_xor(accB.y, off, 64);
            accB.z += __shfl_xor(accB.z, off, 64);
            accB.w += __shfl_xor(accB.w, off, 64);
        }
        if (lane < 8) {
            float4 r0, r1;
            r0.x = fmaxf(accA.x * 0.5f + bb0.x, 0.f);
            r0.y = fmaxf(accA.y * 0.5f + bb0.y, 0.f);
            r0.z = fmaxf(accA.z * 0.5f + bb0.z, 0.f);
            r0.w = fmaxf(accA.w * 0.5f + bb0.w, 0.f);
            r1.x = fmaxf(accB.x * 0.5f + bb1.x, 0.f);
            r1.y = fmaxf(accB.y * 0.5f + bb1.y, 0.f);
            r1.z = fmaxf(accB.z * 0.5f + bb1.z, 0.f);
            r1.w = fmaxf(accB.w * 0.5f + bb1.w, 0.f);
            ((float4*)hout)[(size_t)n * 16 + c8 * 2]     = r0;
            ((float4*)hout)[(size_t)n * 16 + c8 * 2 + 1] = r1;
        }
    }
}

// ============================================================================
// FUSED softmax + gather + classifier MLP (layer 2): writes d_out directly.
// After the xor-reduction ALL lanes hold the h2 channels of their c8 group,
// so the full h2 row is wave-resident — the MLP's K-dim broadcast uses 8
// shfls per k8 group (no LDS RAW, no barrier in the loop). Wm1 first half
// (16 KB) + Wm2 in LDS. Eliminates k_final and the 50 MB h2 round-trip.
// ============================================================================
__global__ __launch_bounds__(256)
void k_ag_mlp(const int* __restrict__ rowptr, const int* __restrict__ csr_src,
              const float* __restrict__ asrc, const float* __restrict__ adst,
              const __half* __restrict__ xph, const float* __restrict__ b,
              const float* __restrict__ cpre, const int* __restrict__ batch,
              const float* __restrict__ Wm1, const float* __restrict__ Wm2,
              const float* __restrict__ bm2, float* __restrict__ out, int N) {
    __shared__ float wm1a[64 * 64];           // Wm1 rows 0..63 (h2 part)
    __shared__ float4 w2l[64];
    for (int i = threadIdx.x; i < 1024; i += 256) ((float4*)wm1a)[i] = ((const float4*)Wm1)[i];
    if (threadIdx.x < 64) w2l[threadIdx.x] = ((const float4*)Wm2)[threadIdx.x];
    __syncthreads();

    int tid = blockIdx.x * blockDim.x + threadIdx.x;
    int lane = threadIdx.x & 63;
    int wid = tid >> 6;
    int nw = (gridDim.x * blockDim.x) >> 6;
    const int l  = lane & 31;
    const int hh = lane >> 5;
    const int g8 = (lane >> 3) & 3;
    const int c8 = lane & 7;
    const uint4* xp4 = (const uint4*)xph;
    float4 bb0 = ((const float4*)b)[c8 * 2];
    float4 bb1 = ((const float4*)b)[c8 * 2 + 1];
    float4 w2 = w2l[lane];
    float4 bm2v = *((const float4*)bm2);

    for (int n = wid; n < N; n += nw) {
        int rs = rowptr[n], re = rowptr[n + 1], cnt = re - rs;
        float a_dst = adst[n * 2 + hh];
        float eself = __expf(lrelu(asrc[n * 2 + hh] + a_dst));

        float4 accA = make_float4(0.f, 0.f, 0.f, 0.f);
        float4 accB = make_float4(0.f, 0.f, 0.f, 0.f);

        if (cnt <= 32) {
            float ev = 0.f; int s_reg = n;
            if (l < cnt) {
                s_reg = csr_src[rs + l];
                ev = __expf(lrelu(asrc[s_reg * 2 + hh] + a_dst));
            }
            float den = ev + (l == 0 ? eself : 0.f);
            #pragma unroll
            for (int off = 16; off > 0; off >>= 1) den += __shfl_xor(den, off, 64);
            float inv = 1.f / (den + 1e-16f);
            float alpha_l = ev * inv;

            if (g8 == 0) acc8(accA, accB, eself * inv, xp4[(size_t)n * 16 + hh * 8 + c8]);
            int base = (hh << 5) - rs;
            for (int e0 = rs; e0 < re; e0 += 8) {
                int ea = e0 + g8, eb = e0 + 4 + g8;
                bool va = ea < re, vb = eb < re;
                float aa = __shfl(alpha_l, base + ea, 64);
                int   sa = __shfl(s_reg,   base + ea, 64);
                float ab = __shfl(alpha_l, base + eb, 64);
                int   sb = __shfl(s_reg,   base + eb, 64);
                if (!va) { aa = 0.f; sa = n; }
                if (!vb) { ab = 0.f; sb = n; }
                uint4 u1 = xp4[(size_t)sa * 16 + hh * 8 + c8];
                uint4 u2 = xp4[(size_t)sb * 16 + hh * 8 + c8];
                acc8(accA, accB, aa, u1);
                acc8(accA, accB, ab, u2);
            }
        } else {
            float den = (l == 0) ? eself : 0.f;
            for (int e = rs + l; e < re; e += 32)
                den += __expf(lrelu(asrc[csr_src[e] * 2 + hh] + a_dst));
            #pragma unroll
            for (int off = 16; off > 0; off >>= 1) den += __shfl_xor(den, off, 64);
            float inv = 1.f / (den + 1e-16f);
            if (g8 == 0) acc8(accA, accB, eself * inv, xp4[(size_t)n * 16 + hh * 8 + c8]);
            for (int e0 = rs; e0 < re; e0 += 8) {
                int ea = e0 + g8, eb = e0 + 4 + g8;
                bool va = ea < re, vb = eb < re;
                int sa = va ? csr_src[ea] : n;
                int sb = vb ? csr_src[eb] : n;
                float aa = va ? __expf(lrelu(asrc[sa * 2 + hh] + a_dst)) * inv : 0.f;
                float ab = vb ? __expf(lrelu(asrc[sb * 2 + hh] + a_dst)) * inv : 0.f;
                uint4 u1 = xp4[(size_t)sa * 16 + hh * 8 + c8];
                uint4 u2 = xp4[(size_t)sb * 16 + hh * 8 + c8];
                acc8(accA, accB, aa, u1);
                acc8(accA, accB, ab, u2);
            }
        }

        #pragma unroll
        for (int off = 8; off <= 32; off <<= 1) {
            accA.x += __shfl_xor(accA.x, off, 64);
            accA.y += __shfl_xor(accA.y, off, 64);
            accA.z += __shfl_xor(accA.z, off, 64);
            accA.w += __shfl_xor(accA.w, off, 64);
            accB.x += __shfl_xor(accB.x, off, 64);
            accB.y += __shfl_xor(accB.y, off, 64);
            accB.z += __shfl_xor(accB.z, off, 64);
            accB.w += __shfl_xor(accB.w, off, 64);
        }
        // h2 channels [c8*8, c8*8+8) — on ALL lanes (full row wave-resident)
        float4 r0, r1;
        r0.x = fmaxf(accA.x * 0.5f + bb0.x, 0.f);
        r0.y = fmaxf(accA.y * 0.5f + bb0.y, 0.f);
        r0.z = fmaxf(accA.z * 0.5f + bb0.z, 0.f);
        r0.w = fmaxf(accA.w * 0.5f + bb0.w, 0.f);
        r1.x = fmaxf(accB.x * 0.5f + bb1.x, 0.f);
        r1.y = fmaxf(accB.y * 0.5f + bb1.y, 0.f);
        r1.z = fmaxf(accB.z * 0.5f + bb1.z, 0.f);
        r1.w = fmaxf(accB.w * 0.5f + bb1.w, 0.f);

        // ---- classifier MLP: m[lane] = cpre[b][lane] + h2 . Wm1a[:,lane] ----
        int bg = batch[n];                                  // wave-uniform
        float m = cpre[(size_t)bg * 64 + lane];             // includes bm1
        #pragma unroll
        for (int k8 = 0; k8 < 8; ++k8) {
            float s0 = __shfl(r0.x, k8, 64), s1 = __shfl(r0.y, k8, 64);
            float s2 = __shfl(r0.z, k8, 64), s3 = __shfl(r0.w, k8, 64);
            float s4 = __shfl(r1.x, k8, 64), s5 = __shfl(r1.y, k8, 64);
            float s6 = __shfl(r1.z, k8, 64), s7 = __shfl(r1.w, k8, 64);
            const float* wr = wm1a + (k8 * 8) * 64 + lane;
            m += s0 * wr[0]   + s1 * wr[64]  + s2 * wr[128] + s3 * wr[192]
               + s4 * wr[256] + s5 * wr[320] + s6 * wr[384] + s7 * wr[448];
        }
        m = fmaxf(m, 0.f);
        float4 p;
        p.x = m * w2.x; p.y = m * w2.y; p.z = m * w2.z; p.w = m * w2.w;
        #pragma unroll
        for (int off = 1; off <= 32; off <<= 1) {
            p.x += __shfl_xor(p.x, off, 64);
            p.y += __shfl_xor(p.y, off, 64);
            p.z += __shfl_xor(p.z, off, 64);
            p.w += __shfl_xor(p.w, off, 64);
        }
        if (lane == 0) {
            float4 o;
            o.x = p.x + bm2v.x; o.y = p.y + bm2v.y;
            o.z = p.z + bm2v.z; o.w = p.w + bm2v.w;
            ((float4*)out)[n] = o;
        }
    }
}

// ============================================================================
// climber embed + cpre fused: cpre[g] = relu(climber@Wc+bc) @ Wm1[64:128] + bm1
// ============================================================================
__global__ __launch_bounds__(256)
void k_climber_cpre(const float* __restrict__ climber, const float* __restrict__ Wc,
                    const float* __restrict__ bc, const float* __restrict__ Wm1,
                    const float* __restrict__ bm1, float* __restrict__ cpre, int G) {
    __shared__ float ce[4][64];
    __shared__ float wm1b[64 * 64];
    int t = threadIdx.x;
    for (int i = t; i < 1024; i += 256) ((float4*)wm1b)[i] = ((const float4*)Wm1)[1024 + i];
    int gl = t >> 6, c = t & 63;
    int g = blockIdx.x * 4 + gl;
    float acc = bc[c];
    if (g < G)
        for (int k = 0; k < 4; ++k) acc += climber[g * 4 + k] * Wc[k * 64 + c];
    ce[gl][c] = fmaxf(acc, 0.f);
    __syncthreads();
    float o = bm1[c];
    for (int k = 0; k < 64; ++k) o += ce[gl][k] * wm1b[k * 64 + c];
    if (g < G) cpre[(size_t)g * 64 + c] = o;
}

extern "C" void kernel_launch(void* const* d_in, const int* in_sizes, int n_in,
                              void* d_out, int out_size, void* d_ws, size_t ws_size,
                              hipStream_t stream) {
    const float* x       = (const float*)d_in[0];
    const int*   ei      = (const int*)  d_in[1];
    const int*   batch   = (const int*)  d_in[2];
    const float* climber = (const float*)d_in[3];
    const float* W1  = (const float*)d_in[4];
    const float* as1 = (const float*)d_in[5];
    const float* ad1 = (const float*)d_in[6];
    const float* b1  = (const float*)d_in[7];
    const float* W2  = (const float*)d_in[8];
    const float* as2 = (const float*)d_in[9];
    const float* ad2 = (const float*)d_in[10];
    const float* b2  = (const float*)d_in[11];
    const float* Wc  = (const float*)d_in[12];
    const float* bc  = (const float*)d_in[13];
    const float* Wm1 = (const float*)d_in[14];
    const float* bm1 = (const float*)d_in[15];
    const float* Wm2 = (const float*)d_in[16];
    const float* bm2 = (const float*)d_in[17];

    const int N  = in_sizes[0] / 6;
    const int E  = in_sizes[1] / 2;
    const int G  = in_sizes[3] / 4;

    const int* srcI = ei;
    const int* dstI = ei + E;

    // ---------------- workspace carve ----------------
    char* base = (char*)d_ws;
    size_t off = 0;
    auto carve = [&](size_t bytes) { void* p = base + off; off += (bytes + 255) & ~size_t(255); return p; };
    __half* xph   = (__half*)carve((size_t)N * 128 * 2);
    float* hbuf   = (float*)carve((size_t)N * 64 * 4);
    float* asrc   = (float*)carve((size_t)N * 2 * 4);
    float* adst   = (float*)carve((size_t)N * 2 * 4);
    float* cpre   = (float*)carve((size_t)G * 64 * 4);
    int*   deg    = (int*)  carve((size_t)N * 4);
    int*   rowptr = (int*)  carve((size_t)(N + 1) * 4);
    int*   rank   = (int*)  carve((size_t)E * 4);
    int*   partial= (int*)  carve(4096 * 4);
    int*   csr_src= (int*)  carve((size_t)E * 4);

    const int tpb = 256;
    const int nScanBlk = (N + 1023) / 1024;
    const int nEdgeBlk = (E + tpb - 1) / tpb;
    const int PG = 2048;
    const int nTile = (N + 63) / 64;

    // ---------------- CSR build (shared by both layers) ----------------
    hipMemsetAsync(deg, 0, (size_t)N * 4, stream);
    k_hist<<<nEdgeBlk, tpb, 0, stream>>>(dstI, deg, rank, E);
    k_scan_partial<<<nScanBlk, tpb, 0, stream>>>(deg, partial, N);
    k_scan_final<<<nScanBlk, tpb, 0, stream>>>(deg, partial, rowptr, N, E, nScanBlk);
    k_scatter<<<nEdgeBlk, tpb, 0, stream>>>(srcI, dstI, rowptr, rank, csr_src, E);

    // ---------------- layer 1 ----------------
    k_xp_gemm<6><<<nTile, tpb, 0, stream>>>(x, W1, as1, ad1, xph, asrc, adst, N);
    k_ag<<<PG, tpb, 0, stream>>>(rowptr, csr_src, asrc, adst, xph, b1, hbuf, N);

    // ---------------- layer 2 (+ fused classifier) ----------------
    k_xp_gemm<64><<<nTile, tpb, 0, stream>>>(hbuf, W2, as2, ad2, xph, asrc, adst, N);
    k_climber_cpre<<<(G + 3) / 4, tpb, 0, stream>>>(climber, Wc, bc, Wm1, bm1, cpre, G);
    k_ag_mlp<<<PG, tpb, 0, stream>>>(rowptr, csr_src, asrc, adst, xph, b2,
                                     cpre, batch, Wm1, Wm2, bm2, (float*)d_out, N);
}

// Round 15
// 340.927 us; speedup vs baseline: 1.2695x; 1.2695x over previous
//
#include <hip/hip_runtime.h>
#include <hip/hip_fp16.h>

#define SLOPE 0.2f

__device__ __forceinline__ float lrelu(float v) { return v >= 0.f ? v : SLOPE * v; }

__device__ __forceinline__ unsigned pack2(float a, float b) {
    __half2 h = __floats2half2_rn(a, b);
    return *reinterpret_cast<unsigned*>(&h);
}
__device__ __forceinline__ float4 h4tof4(uint2 u) {
    __half2 a = *reinterpret_cast<__half2*>(&u.x);
    __half2 b = *reinterpret_cast<__half2*>(&u.y);
    float2 fa = __half22float2(a), fb = __half22float2(b);
    return make_float4(fa.x, fa.y, fb.x, fb.y);
}
__device__ __forceinline__ void acc8(float4& A, float4& B, float a, uint4 u) {
    float4 lo = h4tof4(make_uint2(u.x, u.y));
    float4 hi = h4tof4(make_uint2(u.z, u.w));
    A.x += a * lo.x; A.y += a * lo.y; A.z += a * lo.z; A.w += a * lo.w;
    B.x += a * hi.x; B.y += a * hi.y; B.z += a * hi.z; B.w += a * hi.w;
}

// ============================================================================
// xp = x @ W (K -> 128 = 2 heads * 64) + attention dots, block-tile GEMM.
// 64 nodes/block, 256 threads; cols tx*4 (head 0) + 64+tx*4 (head 1):
// 16B-stride ws reads = 2-way bank access (free, m136).
// ============================================================================
template <int K>
__global__ __launch_bounds__(256)
void k_xp_gemm(const float* __restrict__ x, const float* __restrict__ W,
               const float* __restrict__ as_, const float* __restrict__ ad_,
               __half* __restrict__ xph, float* __restrict__ asrc,
               float* __restrict__ adst, int N) {
    constexpr int ZS = K + 1;
    __shared__ float zs[64 * ZS];
    __shared__ float ws[K * 128];
    const int n0 = blockIdx.x * 64;
    const int t = threadIdx.x;

    for (int i = t; i < K * 32; i += 256) ((float4*)ws)[i] = ((const float4*)W)[i];
    for (int i = t; i < 64 * K; i += 256) {
        int n = i / K, k = i - n * K;
        int gn = n0 + n;
        zs[n * ZS + k] = (gn < N) ? x[(size_t)gn * K + k] : 0.f;
    }
    __syncthreads();

    const int tx = t & 15, ty = t >> 4;
    const int c0a = tx * 4;
    const int c0b = 64 + tx * 4;

    float4 asA = *(const float4*)(as_ + c0a);
    float4 asB = *(const float4*)(as_ + c0b);
    float4 adA = *(const float4*)(ad_ + c0a);
    float4 adB = *(const float4*)(ad_ + c0b);

    float acc[4][8];
    #pragma unroll
    for (int i = 0; i < 4; ++i)
        #pragma unroll
        for (int j = 0; j < 8; ++j) acc[i][j] = 0.f;

    for (int k = 0; k < K; ++k) {
        float4 w0 = *(const float4*)(ws + k * 128 + c0a);
        float4 w1 = *(const float4*)(ws + k * 128 + c0b);
        #pragma unroll
        for (int i = 0; i < 4; ++i) {
            float zv = zs[(ty * 4 + i) * ZS + k];
            acc[i][0] += zv * w0.x; acc[i][1] += zv * w0.y;
            acc[i][2] += zv * w0.z; acc[i][3] += zv * w0.w;
            acc[i][4] += zv * w1.x; acc[i][5] += zv * w1.y;
            acc[i][6] += zv * w1.z; acc[i][7] += zv * w1.w;
        }
    }

    #pragma unroll
    for (int i = 0; i < 4; ++i) {
        int nl = ty * 4 + i, gn = n0 + nl;
        if (gn < N) {
            uint2 ua, ub;
            ua.x = pack2(acc[i][0], acc[i][1]);
            ua.y = pack2(acc[i][2], acc[i][3]);
            ub.x = pack2(acc[i][4], acc[i][5]);
            ub.y = pack2(acc[i][6], acc[i][7]);
            *(uint2*)(xph + (size_t)gn * 128 + c0a) = ua;
            *(uint2*)(xph + (size_t)gn * 128 + c0b) = ub;
        }
        float ps0 = acc[i][0]*asA.x + acc[i][1]*asA.y + acc[i][2]*asA.z + acc[i][3]*asA.w;
        float ps1 = acc[i][4]*asB.x + acc[i][5]*asB.y + acc[i][6]*asB.z + acc[i][7]*asB.w;
        float pd0 = acc[i][0]*adA.x + acc[i][1]*adA.y + acc[i][2]*adA.z + acc[i][3]*adA.w;
        float pd1 = acc[i][4]*adB.x + acc[i][5]*adB.y + acc[i][6]*adB.z + acc[i][7]*adB.w;
        #pragma unroll
        for (int off = 1; off <= 8; off <<= 1) {
            ps0 += __shfl_xor(ps0, off, 64);
            ps1 += __shfl_xor(ps1, off, 64);
            pd0 += __shfl_xor(pd0, off, 64);
            pd1 += __shfl_xor(pd1, off, 64);
        }
        if (tx == 0 && gn < N) {
            asrc[gn * 2]     = ps0;
            asrc[gn * 2 + 1] = ps1;
            adst[gn * 2]     = pd0;
            adst[gn * 2 + 1] = pd1;
        }
    }
}

// ============================================================================
// CSR build: histogram(+rank capture) -> scan -> atomic-free scatter.
// rank[e] decouples the scatter store from the atomic round-trip (R13 win).
// ============================================================================
__global__ void k_hist(const int* __restrict__ dst, int* __restrict__ deg,
                       int* __restrict__ rank, int E) {
    int e = blockIdx.x * blockDim.x + threadIdx.x;
    if (e < E) rank[e] = atomicAdd(&deg[dst[e]], 1);
}

__global__ void k_scan_partial(const int* __restrict__ deg, int* __restrict__ partial, int N) {
    int b = blockIdx.x, t = threadIdx.x;
    int base = b * 1024 + t * 4;
    int s = 0;
    for (int i = 0; i < 4; ++i) { int idx = base + i; if (idx < N) s += deg[idx]; }
    __shared__ int sh[256];
    sh[t] = s; __syncthreads();
    for (int off = 128; off > 0; off >>= 1) { if (t < off) sh[t] += sh[t + off]; __syncthreads(); }
    if (t == 0) partial[b] = sh[0];
}

__global__ void k_scan_final(const int* __restrict__ deg, const int* __restrict__ partial,
                             int* __restrict__ rowptr, int N, int E, int nb) {
    int b = blockIdx.x, t = threadIdx.x;
    __shared__ int shp[256];
    shp[t] = (t < nb) ? partial[t] : 0;
    __syncthreads();
    for (int off = 1; off < 256; off <<= 1) {
        int v = (t >= off) ? shp[t - off] : 0;
        __syncthreads();
        shp[t] += v;
        __syncthreads();
    }
    int pbase = (b > 0) ? shp[b - 1] : 0;
    __syncthreads();

    int base = b * 1024 + t * 4;
    int local[4]; int s = 0;
    for (int i = 0; i < 4; ++i) { int idx = base + i; local[i] = (idx < N) ? deg[idx] : 0; s += local[i]; }
    __shared__ int sh[256];
    int orig = s;
    sh[t] = s; __syncthreads();
    for (int off = 1; off < 256; off <<= 1) {
        int v = (t >= off) ? sh[t - off] : 0;
        __syncthreads();
        sh[t] += v;
        __syncthreads();
    }
    int run = pbase + sh[t] - orig;
    for (int i = 0; i < 4; ++i) {
        int idx = base + i;
        if (idx < N) rowptr[idx] = run;
        run += local[i];
    }
    if (b == 0 && t == 0) rowptr[N] = E;
}

__global__ void k_scatter(const int* __restrict__ src, const int* __restrict__ dst,
                          const int* __restrict__ rowptr, const int* __restrict__ rank,
                          int* __restrict__ csr_src, int E) {
    int e = blockIdx.x * blockDim.x + threadIdx.x;
    if (e >= E) return;
    int d = dst[e];
    csr_src[rowptr[d] + rank[e]] = src[e];
}

// ============================================================================
// FUSED softmax + gather (R9 v2): one wave per node, no max-subtraction,
// register-alpha + shfl broadcast, 16 B gathers, 8 edges/head in flight.
// NOTE (R14): do NOT fuse the classifier MLP in here — the +16KB LDS /
// +40 VGPR epilogue halves occupancy (65%->29%) and triples duration; this
// kernel's gather phase lives on wave oversubscription.
// ============================================================================
__global__ void k_ag(const int* __restrict__ rowptr, const int* __restrict__ csr_src,
                     const float* __restrict__ asrc, const float* __restrict__ adst,
                     const __half* __restrict__ xph, const float* __restrict__ b,
                     float* __restrict__ hout, int N) {
    int tid = blockIdx.x * blockDim.x + threadIdx.x;
    int lane = threadIdx.x & 63;
    int wid = tid >> 6;
    int nw = (gridDim.x * blockDim.x) >> 6;
    const int l  = lane & 31;
    const int hh = lane >> 5;
    const int g8 = (lane >> 3) & 3;
    const int c8 = lane & 7;
    const uint4* xp4 = (const uint4*)xph;
    float4 bb0 = ((const float4*)b)[c8 * 2];
    float4 bb1 = ((const float4*)b)[c8 * 2 + 1];

    for (int n = wid; n < N; n += nw) {
        int rs = rowptr[n], re = rowptr[n + 1], cnt = re - rs;
        float a_dst = adst[n * 2 + hh];
        float eself = __expf(lrelu(asrc[n * 2 + hh] + a_dst));

        float4 accA = make_float4(0.f, 0.f, 0.f, 0.f);
        float4 accB = make_float4(0.f, 0.f, 0.f, 0.f);

        if (cnt <= 32) {
            float ev = 0.f; int s_reg = n;
            if (l < cnt) {
                s_reg = csr_src[rs + l];
                ev = __expf(lrelu(asrc[s_reg * 2 + hh] + a_dst));
            }
            float den = ev + (l == 0 ? eself : 0.f);
            #pragma unroll
            for (int off = 16; off > 0; off >>= 1) den += __shfl_xor(den, off, 64);
            float inv = 1.f / (den + 1e-16f);
            float alpha_l = ev * inv;

            if (g8 == 0) acc8(accA, accB, eself * inv, xp4[(size_t)n * 16 + hh * 8 + c8]);
            int base = (hh << 5) - rs;
            for (int e0 = rs; e0 < re; e0 += 8) {
                int ea = e0 + g8, eb = e0 + 4 + g8;
                bool va = ea < re, vb = eb < re;
                float aa = __shfl(alpha_l, base + ea, 64);
                int   sa = __shfl(s_reg,   base + ea, 64);
                float ab = __shfl(alpha_l, base + eb, 64);
                int   sb = __shfl(s_reg,   base + eb, 64);
                if (!va) { aa = 0.f; sa = n; }
                if (!vb) { ab = 0.f; sb = n; }
                uint4 u1 = xp4[(size_t)sa * 16 + hh * 8 + c8];
                uint4 u2 = xp4[(size_t)sb * 16 + hh * 8 + c8];
                acc8(accA, accB, aa, u1);
                acc8(accA, accB, ab, u2);
            }
        } else {
            float den = (l == 0) ? eself : 0.f;
            for (int e = rs + l; e < re; e += 32)
                den += __expf(lrelu(asrc[csr_src[e] * 2 + hh] + a_dst));
            #pragma unroll
            for (int off = 16; off > 0; off >>= 1) den += __shfl_xor(den, off, 64);
            float inv = 1.f / (den + 1e-16f);
            if (g8 == 0) acc8(accA, accB, eself * inv, xp4[(size_t)n * 16 + hh * 8 + c8]);
            for (int e0 = rs; e0 < re; e0 += 8) {
                int ea = e0 + g8, eb = e0 + 4 + g8;
                bool va = ea < re, vb = eb < re;
                int sa = va ? csr_src[ea] : n;
                int sb = vb ? csr_src[eb] : n;
                float aa = va ? __expf(lrelu(asrc[sa * 2 + hh] + a_dst)) * inv : 0.f;
                float ab = vb ? __expf(lrelu(asrc[sb * 2 + hh] + a_dst)) * inv : 0.f;
                uint4 u1 = xp4[(size_t)sa * 16 + hh * 8 + c8];
                uint4 u2 = xp4[(size_t)sb * 16 + hh * 8 + c8];
                acc8(accA, accB, aa, u1);
                acc8(accA, accB, ab, u2);
            }
        }

        #pragma unroll
        for (int off = 8; off <= 32; off <<= 1) {
            accA.x += __shfl_xor(accA.x, off, 64);
            accA.y += __shfl_xor(accA.y, off, 64);
            accA.z += __shfl_xor(accA.z, off, 64);
            accA.w += __shfl_xor(accA.w, off, 64);
            accB.x += __shfl_xor(accB.x, off, 64);
            accB.y += __shfl_xor(accB.y, off, 64);
            accB.z += __shfl_xor(accB.z, off, 64);
            accB.w += __shfl_xor(accB.w, off, 64);
        }
        if (lane < 8) {
            float4 r0, r1;
            r0.x = fmaxf(accA.x * 0.5f + bb0.x, 0.f);
            r0.y = fmaxf(accA.y * 0.5f + bb0.y, 0.f);
            r0.z = fmaxf(accA.z * 0.5f + bb0.z, 0.f);
            r0.w = fmaxf(accA.w * 0.5f + bb0.w, 0.f);
            r1.x = fmaxf(accB.x * 0.5f + bb1.x, 0.f);
            r1.y = fmaxf(accB.y * 0.5f + bb1.y, 0.f);
            r1.z = fmaxf(accB.z * 0.5f + bb1.z, 0.f);
            r1.w = fmaxf(accB.w * 0.5f + bb1.w, 0.f);
            ((float4*)hout)[(size_t)n * 16 + c8 * 2]     = r0;
            ((float4*)hout)[(size_t)n * 16 + c8 * 2 + 1] = r1;
        }
    }
}

// ============================================================================
// climber embed + cpre fused: cpre[g] = relu(climber@Wc+bc) @ Wm1[64:128] + bm1
// ============================================================================
__global__ __launch_bounds__(256)
void k_climber_cpre(const float* __restrict__ climber, const float* __restrict__ Wc,
                    const float* __restrict__ bc, const float* __restrict__ Wm1,
                    const float* __restrict__ bm1, float* __restrict__ cpre, int G) {
    __shared__ float ce[4][64];
    __shared__ float wm1b[64 * 64];
    int t = threadIdx.x;
    for (int i = t; i < 1024; i += 256) ((float4*)wm1b)[i] = ((const float4*)Wm1)[1024 + i];
    int gl = t >> 6, c = t & 63;
    int g = blockIdx.x * 4 + gl;
    float acc = bc[c];
    if (g < G)
        for (int k = 0; k < 4; ++k) acc += climber[g * 4 + k] * Wc[k * 64 + c];
    ce[gl][c] = fmaxf(acc, 0.f);
    __syncthreads();
    float o = bm1[c];
    for (int k = 0; k < 64; ++k) o += ce[gl][k] * wm1b[k * 64 + c];
    if (g < G) cpre[(size_t)g * 64 + c] = o;
}

// ============================================================================
// Final MLP, block-tile GEMM: 64 nodes/block, 256 threads, 4x4 micro-tile.
// Kept SEPARATE from k_ag (see R14 note above).
// ============================================================================
__global__ __launch_bounds__(256)
void k_final(const float* __restrict__ h2, const float* __restrict__ cpre,
             const int* __restrict__ batch, const float* __restrict__ Wm1,
             const float* __restrict__ Wm2, const float* __restrict__ bm2,
             float* __restrict__ out, int N) {
    __shared__ float zs[64 * 65];
    __shared__ float ws[64 * 64];
    __shared__ float4 w2l[64];
    const int n0 = blockIdx.x * 64;
    const int t = threadIdx.x;

    for (int i = t; i < 1024; i += 256) ((float4*)ws)[i] = ((const float4*)Wm1)[i];
    if (t < 64) w2l[t] = ((const float4*)Wm2)[t];
    for (int i = t; i < 64 * 64; i += 256) {
        int n = i >> 6, k = i & 63;
        int gn = n0 + n;
        zs[n * 65 + k] = (gn < N) ? h2[(size_t)gn * 64 + k] : 0.f;
    }
    __syncthreads();

    const int tx = t & 15, ty = t >> 4;
    const int c0 = tx * 4;
    float acc[4][4];
    #pragma unroll
    for (int i = 0; i < 4; ++i)
        #pragma unroll
        for (int j = 0; j < 4; ++j) acc[i][j] = 0.f;

    for (int k = 0; k < 64; ++k) {
        float4 wv = *(const float4*)(ws + k * 64 + c0);
        #pragma unroll
        for (int i = 0; i < 4; ++i) {
            float zv = zs[(ty * 4 + i) * 65 + k];
            acc[i][0] += zv * wv.x; acc[i][1] += zv * wv.y;
            acc[i][2] += zv * wv.z; acc[i][3] += zv * wv.w;
        }
    }
    __syncthreads();

    float4 wa = w2l[c0], wb = w2l[c0 + 1], wc = w2l[c0 + 2], wd = w2l[c0 + 3];
    #pragma unroll
    for (int i = 0; i < 4; ++i) {
        int nl = ty * 4 + i, gn = n0 + nl;
        float4 o = make_float4(0.f, 0.f, 0.f, 0.f);
        if (gn < N) {
            int b = batch[gn];
            float4 cp = *(const float4*)(cpre + (size_t)b * 64 + c0);
            float m0 = fmaxf(acc[i][0] + cp.x, 0.f);
            float m1 = fmaxf(acc[i][1] + cp.y, 0.f);
            float m2 = fmaxf(acc[i][2] + cp.z, 0.f);
            float m3 = fmaxf(acc[i][3] + cp.w, 0.f);
            o.x = m0 * wa.x + m1 * wb.x + m2 * wc.x + m3 * wd.x;
            o.y = m0 * wa.y + m1 * wb.y + m2 * wc.y + m3 * wd.y;
            o.z = m0 * wa.z + m1 * wb.z + m2 * wc.z + m3 * wd.z;
            o.w = m0 * wa.w + m1 * wb.w + m2 * wc.w + m3 * wd.w;
        }
        *(float4*)(zs + tx * 260 + nl * 4) = o;
    }
    __syncthreads();
    {
        int nl = t >> 2, j = t & 3, gn = n0 + nl;
        float s = 0.f;
        #pragma unroll
        for (int tx2 = 0; tx2 < 16; ++tx2) s += zs[tx2 * 260 + nl * 4 + j];
        if (gn < N) out[(size_t)gn * 4 + j] = s + bm2[j];
    }
}

extern "C" void kernel_launch(void* const* d_in, const int* in_sizes, int n_in,
                              void* d_out, int out_size, void* d_ws, size_t ws_size,
                              hipStream_t stream) {
    const float* x       = (const float*)d_in[0];
    const int*   ei      = (const int*)  d_in[1];
    const int*   batch   = (const int*)  d_in[2];
    const float* climber = (const float*)d_in[3];
    const float* W1  = (const float*)d_in[4];
    const float* as1 = (const float*)d_in[5];
    const float* ad1 = (const float*)d_in[6];
    const float* b1  = (const float*)d_in[7];
    const float* W2  = (const float*)d_in[8];
    const float* as2 = (const float*)d_in[9];
    const float* ad2 = (const float*)d_in[10];
    const float* b2  = (const float*)d_in[11];
    const float* Wc  = (const float*)d_in[12];
    const float* bc  = (const float*)d_in[13];
    const float* Wm1 = (const float*)d_in[14];
    const float* bm1 = (const float*)d_in[15];
    const float* Wm2 = (const float*)d_in[16];
    const float* bm2 = (const float*)d_in[17];

    const int N  = in_sizes[0] / 6;
    const int E  = in_sizes[1] / 2;
    const int G  = in_sizes[3] / 4;

    const int* srcI = ei;
    const int* dstI = ei + E;

    // ---------------- workspace carve ----------------
    char* base = (char*)d_ws;
    size_t off = 0;
    auto carve = [&](size_t bytes) { void* p = base + off; off += (bytes + 255) & ~size_t(255); return p; };
    __half* xph   = (__half*)carve((size_t)N * 128 * 2);
    float* hbuf   = (float*)carve((size_t)N * 64 * 4);
    float* asrc   = (float*)carve((size_t)N * 2 * 4);
    float* adst   = (float*)carve((size_t)N * 2 * 4);
    float* cpre   = (float*)carve((size_t)G * 64 * 4);
    int*   deg    = (int*)  carve((size_t)N * 4);
    int*   rowptr = (int*)  carve((size_t)(N + 1) * 4);
    int*   rank   = (int*)  carve((size_t)E * 4);
    int*   partial= (int*)  carve(4096 * 4);
    int*   csr_src= (int*)  carve((size_t)E * 4);

    const int tpb = 256;
    const int nScanBlk = (N + 1023) / 1024;
    const int nEdgeBlk = (E + tpb - 1) / tpb;
    const int PG = 2048;
    const int nTile = (N + 63) / 64;

    // ---------------- CSR build (shared by both layers) ----------------
    hipMemsetAsync(deg, 0, (size_t)N * 4, stream);
    k_hist<<<nEdgeBlk, tpb, 0, stream>>>(dstI, deg, rank, E);
    k_scan_partial<<<nScanBlk, tpb, 0, stream>>>(deg, partial, N);
    k_scan_final<<<nScanBlk, tpb, 0, stream>>>(deg, partial, rowptr, N, E, nScanBlk);
    k_scatter<<<nEdgeBlk, tpb, 0, stream>>>(srcI, dstI, rowptr, rank, csr_src, E);

    // ---------------- layer 1 ----------------
    k_xp_gemm<6><<<nTile, tpb, 0, stream>>>(x, W1, as1, ad1, xph, asrc, adst, N);
    k_ag<<<PG, tpb, 0, stream>>>(rowptr, csr_src, asrc, adst, xph, b1, hbuf, N);

    // ---------------- layer 2 ----------------
    k_xp_gemm<64><<<nTile, tpb, 0, stream>>>(hbuf, W2, as2, ad2, xph, asrc, adst, N);
    k_ag<<<PG, tpb, 0, stream>>>(rowptr, csr_src, asrc, adst, xph, b2, hbuf, N);

    // ---------------- classifier ----------------
    k_climber_cpre<<<(G + 3) / 4, tpb, 0, stream>>>(climber, Wc, bc, Wm1, bm1, cpre, G);
    k_final<<<nTile, tpb, 0, stream>>>(hbuf, cpre, batch, Wm1, Wm2, bm2, (float*)d_out, N);
}